// Round 8
// baseline (195.819 us; speedup 1.0000x reference)
//
#include <hip/hip_runtime.h>
#include <hip/hip_bf16.h>

// Problem constants
#define D       512       // embedding dim (= C)
#define K       2048      // codebook size
#define HW      1024      // 32*32
#define N_TOK   16384     // 16*HW
#define NUMEL   8388608   // 16*512*32*32

typedef __attribute__((ext_vector_type(8))) short  short8;   // 8 bf16 = 4 VGPRs
typedef __attribute__((ext_vector_type(4))) float  floatx4;

// async global->LDS DMA, 16 B per lane; LDS dest is wave-uniform base + lane*16
#define GLD_LDS16(gptr, lptr) \
    __builtin_amdgcn_global_load_lds((const __attribute__((address_space(1))) void*)(gptr), \
                                     (__attribute__((address_space(3))) void*)(lptr), 16, 0, 0)

// ---- ws layout (bytes) ----
#define WS_ZB    0           // bf16 [16384][512]
#define WS_EB    16777216    // bf16 [2048][512]
#define WS_ESQ   18874368    // f32  [2048]
#define WS_MINB  18882560    // u32  [16384] packed (21-bit dist key | 11-bit idx); init in kp
#define WS_PZ    18948096    // f32  [2048]  per-kp-block sum z^2 partials (written, no init)
#define WS_PARTS 18956288    // f32  [256]   per-strip decoded-key partials (written, no init)
#define WS_CNT2  18957312    // u32  [1]     completion counter (memset 0 — only memset!)

// monotone fp32 -> sortable u32, and its inverse
__device__ __forceinline__ unsigned int fkey(float f) {
    unsigned int b = __float_as_uint(f);
    return b ^ ((unsigned int)((int)b >> 31) | 0x80000000u);
}
__device__ __forceinline__ float unfkey(unsigned int u) {
    unsigned int b = (u & 0x80000000u) ? (u ^ 0x80000000u) : ~u;
    return __uint_as_float(b);
}

// ---------------- Kernel P: fused prep ----------------
// blocks [0,2048): z NCHW fp32 -> zb bf16 (transpose+cast) + sum(z^2) partial + minb init
// blocks [2048,4096): emb row -> eb bf16 + e_sq
__global__ __launch_bounds__(256) void kp(const float* __restrict__ z,
                                          const float* __restrict__ emb,
                                          __hip_bfloat16* __restrict__ zb,
                                          __hip_bfloat16* __restrict__ eb,
                                          float* __restrict__ esq,
                                          float* __restrict__ pz,
                                          unsigned int* __restrict__ minb) {
    int blk = blockIdx.x;
    int tid = threadIdx.x;
    if (blk < 2048) {
        if (tid < 8) minb[blk * 8 + tid] = 0xFFFFFFFFu;
        __shared__ float t[64][65];
        __shared__ float ls[4];
        int b  = blk >> 7;
        int dt = (blk >> 4) & 7;
        int nt = blk & 15;
        int d0 = dt * 64, n0 = nt * 64;
        const float* zp = z + ((size_t)b * D + d0) * HW + n0;
        float s = 0.f;                      // z^2 partial, computed inline on load
#pragma unroll
        for (int i = 0; i < 4; ++i) {
            int e = tid + 256 * i;          // r(64 ch) x c4(16)
            int r = e >> 4, c4 = e & 15;
            float4 v = *(const float4*)(zp + (size_t)r * HW + c4 * 4);
            s += v.x * v.x + v.y * v.y + v.z * v.z + v.w * v.w;
            t[r][c4 * 4 + 0] = v.x; t[r][c4 * 4 + 1] = v.y;
            t[r][c4 * 4 + 2] = v.z; t[r][c4 * 4 + 3] = v.w;
        }
#pragma unroll
        for (int o = 32; o; o >>= 1) s += __shfl_down(s, o);
        if ((tid & 63) == 0) ls[tid >> 6] = s;
        __syncthreads();
        if (tid == 0) pz[blk] = ls[0] + ls[1] + ls[2] + ls[3];   // plain store, no atomic
        // transposed store: 16 B short8 per store (rn = token, cd8 = channel octet)
        __hip_bfloat16* op = zb + ((size_t)(b * HW + n0)) * D + d0;
#pragma unroll
        for (int i = 0; i < 2; ++i) {
            int e = tid + 256 * i;          // 0..511 : rn(64) x cd8(8)
            int rn = e >> 3, cd8 = e & 7;
            short8 pk;
#pragma unroll
            for (int j = 0; j < 8; ++j) {
                __hip_bfloat16 h = __float2bfloat16(t[cd8 * 8 + j][rn]);   // 2-way banks: free
                pk[j] = *(short*)&h;
            }
            *(short8*)(op + (size_t)rn * D + cd8 * 8) = pk;
        }
    } else {
        int k = blk - 2048;
        const float* ep = emb + (size_t)k * D;
        float s = 0.f;
        for (int d = tid; d < D; d += 256) {
            float v = ep[d];
            s += v * v;
            eb[(size_t)k * D + d] = __float2bfloat16(v);
        }
#pragma unroll
        for (int o = 32; o; o >>= 1) s += __shfl_down(s, o);
        __shared__ float ls[4];
        if ((tid & 63) == 0) ls[tid >> 6] = s;
        __syncthreads();
        if (tid == 0) esq[k] = ls[0] + ls[1] + ls[2] + ls[3];
    }
}

// ---------------- Kernel G: bf16 MFMA GEMM + fused argmin (R4-proven, ~65 us) ----------------
// grid 2048 blocks = 128 mtiles x 16 ktiles (16 consecutive blocks share the A strip,
// dispatched simultaneously across XCDs). LDS XOR col swizzle -> 0 bank conflicts.
__global__ __launch_bounds__(256) void kg(const __hip_bfloat16* __restrict__ zb,
                                          const __hip_bfloat16* __restrict__ eb,
                                          const float* __restrict__ esq,
                                          unsigned int* __restrict__ minb) {
    __shared__ __hip_bfloat16 As[128 * 64];   // flat, unpadded (global_load_lds dest)
    __shared__ __hip_bfloat16 Bs[128 * 64];

    int mtile = blockIdx.x >> 4;
    int ktile = blockIdx.x & 15;

    int tid  = threadIdx.x;
    int wv   = tid >> 6;
    int lane = tid & 63;
    int wm = wv >> 1, wn = wv & 1;   // 2x2 wave grid, each wave 64x64
    int lrow  = lane & 15;
    int lquad = lane >> 4;
    int rl = lane >> 3, c8 = lane & 7;      // staging: 8 rows x 8 uint4 per wave-call
    int csw = c8 ^ rl;                      // swizzled global col for this lane's slot
    int swz = lrow & 7;                     // read-side row swizzle

    floatx4 acc[4][4];
#pragma unroll
    for (int i = 0; i < 4; ++i)
#pragma unroll
        for (int j = 0; j < 4; ++j) acc[i][j] = (floatx4){0.f, 0.f, 0.f, 0.f};

    const uint4* Ag = (const uint4*)(zb + (size_t)mtile * 128 * D);  // [128][64] uint4
    const uint4* Bg = (const uint4*)(eb + (size_t)ktile * 128 * D);

    for (int d0 = 0; d0 < D; d0 += 64) {
        int c0 = d0 >> 3;   // uint4 col offset
#pragma unroll
        for (int ch = 0; ch < 4; ++ch) {
            int rbase = wv * 32 + ch * 8;    // wave-uniform
            GLD_LDS16(Ag + (size_t)(rbase + rl) * 64 + c0 + csw, &As[rbase * 64]);
            GLD_LDS16(Bg + (size_t)(rbase + rl) * 64 + c0 + csw, &Bs[rbase * 64]);
        }
        __syncthreads();
#pragma unroll
        for (int ks = 0; ks < 2; ++ks) {
            short8 af[4], bfr[4];
#pragma unroll
            for (int i = 0; i < 4; ++i) {
                int cL = (ks * 4 + lquad) ^ swz;          // swizzled uint4 col
                af[i]  = *(const short8*)&As[(wm * 64 + i * 16 + lrow) * 64 + (cL << 3)];
                bfr[i] = *(const short8*)&Bs[(wn * 64 + i * 16 + lrow) * 64 + (cL << 3)];
            }
#pragma unroll
            for (int i = 0; i < 4; ++i)
#pragma unroll
                for (int j = 0; j < 4; ++j)
                    acc[i][j] = __builtin_amdgcn_mfma_f32_16x16x32_bf16(af[i], bfr[j], acc[i][j], 0, 0, 0);
        }
        __syncthreads();
    }

    // epilogue: dist = esq[k] - 2*dot; argmin via u32 key = trunc-fkey | idx
    float es[4];
#pragma unroll
    for (int j = 0; j < 4; ++j) es[j] = esq[ktile * 128 + wn * 64 + j * 16 + lrow];

#pragma unroll
    for (int i = 0; i < 4; ++i) {
#pragma unroll
        for (int r = 0; r < 4; ++r) {
            int m_g = mtile * 128 + wm * 64 + i * 16 + lquad * 4 + r;  // C/D: row=quad*4+reg
            unsigned int best = 0xFFFFFFFFu;
#pragma unroll
            for (int j = 0; j < 4; ++j) {
                float dist = es[j] - 2.0f * acc[i][j][r];
                unsigned int kidx = (unsigned int)(ktile * 128 + wn * 64 + j * 16 + lrow);
                unsigned int p = (fkey(dist) & 0xFFFFF800u) | kidx;
                best = p < best ? p : best;
            }
#pragma unroll
            for (int o = 1; o < 16; o <<= 1) {
                unsigned int other = __shfl_xor(best, o);
                best = other < best ? other : best;
            }
            if (lrow == 0) atomicMin(&minb[m_g], best);
        }
    }
}

// ---------------- Kernel O4: gather + NCHW write + loss ----------------
// 2048 blocks x 256 thr (~8 blocks/CU): block = 64-token strip x 64-channel tile.
// ct==0 blocks also produce the strip's decoded-key loss partial; the
// last-finishing one folds in sum(pz) and finalizes the loss.
__global__ __launch_bounds__(256) void ko4(const float* __restrict__ emb,
                                           const unsigned int* __restrict__ minb,
                                           const float* __restrict__ pz,
                                           float* __restrict__ out,
                                           float* __restrict__ parts,
                                           unsigned int* __restrict__ cnt2) {
    __shared__ int idx[64];
    __shared__ float qt[64][65];      // 65-stride: conflict-free both phases
    __shared__ float red[4];
    __shared__ int finflag;
    int blk = blockIdx.x;
    int strip = blk >> 3;             // 0..255 : token strip (b, hw0..hw0+63)
    int ct = blk & 7;                 // channel tile
    int b = strip >> 4, hw0 = (strip & 15) * 64;
    int c0 = ct * 64;
    int tid = threadIdx.x;
    unsigned int mykey = 0;
    if (tid < 64) {
        mykey = minb[strip * 64 + tid];
        idx[tid] = (int)(mykey & 0x7FFu);
    }
    if (tid == 0) finflag = 0;
    __syncthreads();
    // gather: 64 rows x 16 float4 (256 B coalesced per row; codebook is L2-hot)
#pragma unroll
    for (int i = 0; i < 4; ++i) {
        int e = tid + 256 * i;        // tr(64) x c4(16)
        int tr = e >> 4, c4 = e & 15;
        float4 v = *(const float4*)(emb + (size_t)idx[tr] * D + c0 + c4 * 4);
        qt[tr][c4 * 4 + 0] = v.x; qt[tr][c4 * 4 + 1] = v.y;
        qt[tr][c4 * 4 + 2] = v.z; qt[tr][c4 * 4 + 3] = v.w;
    }
    // loss partial: ct==0 blocks, wave 0 (covers each token exactly once)
    if (ct == 0 && tid < 64) {
        float v = unfkey(mykey & 0xFFFFF800u);
#pragma unroll
        for (int o = 32; o; o >>= 1) v += __shfl_down(v, o);
        if (tid == 0) {
            parts[strip] = v;
            __threadfence();
            finflag = (atomicAdd(cnt2, 1u) == 255u);
        }
    }
    __syncthreads();                  // qt ready (and finflag visible)
    float* op = out + ((size_t)b * D + c0) * HW + hw0;
#pragma unroll
    for (int i = 0; i < 4; ++i) {
        int e = tid + 256 * i;        // r(64 ch) x h4(16), float4 along hw
        int r = e >> 4, h4 = e & 15;
        float4 q;
        q.x = qt[h4 * 4 + 0][r]; q.y = qt[h4 * 4 + 1][r];
        q.z = qt[h4 * 4 + 2][r]; q.w = qt[h4 * 4 + 3][r];
        *(float4*)(op + (size_t)r * HW + h4 * 4) = q;
    }
    // finalize: last ct==0 block sums 256 strip partials + 2048 z^2 partials
    if (finflag) {
        float s = atomicAdd(&parts[tid], 0.0f);     // coherent read of partials
#pragma unroll
        for (int k8 = 0; k8 < 8; ++k8) s += pz[tid * 8 + k8];  // written pre-kg: visible
#pragma unroll
        for (int o = 32; o; o >>= 1) s += __shfl_down(s, o);
        if ((tid & 63) == 0) red[tid >> 6] = s;
        __syncthreads();
        if (tid == 0)
            out[NUMEL] = 1.25f * (red[0] + red[1] + red[2] + red[3]) / 8388608.0f;
    }
}

extern "C" void kernel_launch(void* const* d_in, const int* in_sizes, int n_in,
                              void* d_out, int out_size, void* d_ws, size_t ws_size,
                              hipStream_t stream) {
    const float* z   = (const float*)d_in[0];   // [16,512,32,32]
    const float* emb = (const float*)d_in[1];   // [2048,512]
    char* ws = (char*)d_ws;
    __hip_bfloat16* zb   = (__hip_bfloat16*)(ws + WS_ZB);
    __hip_bfloat16* eb   = (__hip_bfloat16*)(ws + WS_EB);
    float*          esq  = (float*)(ws + WS_ESQ);
    unsigned int*   minb = (unsigned int*)(ws + WS_MINB);
    float*          pz   = (float*)(ws + WS_PZ);
    float*          parts= (float*)(ws + WS_PARTS);
    unsigned int*   cnt2 = (unsigned int*)(ws + WS_CNT2);
    float* out = (float*)d_out;

    hipMemsetAsync(cnt2, 0, 4, stream);     // the only init needed
    kp <<<4096, 256, 0, stream>>>(z, emb, zb, eb, esq, pz, minb);
    kg <<<2048, 256, 0, stream>>>(zb, eb, esq, minb);
    ko4<<<2048, 256, 0, stream>>>(emb, minb, pz, out, parts, cnt2);
}

// Round 9
// 162.538 us; speedup vs baseline: 1.2048x; 1.2048x over previous
//
#include <hip/hip_runtime.h>
#include <hip/hip_bf16.h>

// Problem constants
#define D       512       // embedding dim (= C)
#define K       2048      // codebook size
#define HW      1024      // 32*32
#define N_TOK   16384     // 16*HW
#define NUMEL   8388608   // 16*512*32*32

typedef __attribute__((ext_vector_type(8))) short  short8;   // 8 bf16 = 4 VGPRs
typedef __attribute__((ext_vector_type(4))) float  floatx4;

// async global->LDS DMA, 16 B per lane; LDS dest is wave-uniform base + lane*16
#define GLD_LDS16(gptr, lptr) \
    __builtin_amdgcn_global_load_lds((const __attribute__((address_space(1))) void*)(gptr), \
                                     (__attribute__((address_space(3))) void*)(lptr), 16, 0, 0)

// ---- ws layout (bytes) ----
#define WS_ZB    0           // bf16 [16384][512]
#define WS_EB    16777216    // bf16 [2048][512]
#define WS_ESQ   18874368    // f32  [2048]
#define WS_MINB  18882560    // u32  [16384] packed (21-bit dist key | 11-bit idx); init in kp
#define WS_PZ    18948096    // f32  [2048]  per-kp-block sum z^2 partials (plain writes)
#define WS_PARTS 18956288    // f32  [256]   per-strip decoded-key partials (plain writes)
#define WS_CNT2  18957312    // u32  [1]     completion counter (zeroed by kp)

// monotone fp32 -> sortable u32, and its inverse
__device__ __forceinline__ unsigned int fkey(float f) {
    unsigned int b = __float_as_uint(f);
    return b ^ ((unsigned int)((int)b >> 31) | 0x80000000u);
}
__device__ __forceinline__ float unfkey(unsigned int u) {
    unsigned int b = (u & 0x80000000u) ? (u ^ 0x80000000u) : ~u;
    return __uint_as_float(b);
}

// ---------------- Kernel P: fused prep ----------------
// blocks [0,2048): z NCHW fp32 -> zb bf16 (transpose+cast) + sum(z^2) partial + minb/cnt2 init
// blocks [2048,4096): emb row -> eb bf16 + e_sq
__global__ __launch_bounds__(256) void kp(const float* __restrict__ z,
                                          const float* __restrict__ emb,
                                          __hip_bfloat16* __restrict__ zb,
                                          __hip_bfloat16* __restrict__ eb,
                                          float* __restrict__ esq,
                                          float* __restrict__ pz,
                                          unsigned int* __restrict__ minb,
                                          unsigned int* __restrict__ cnt2) {
    int blk = blockIdx.x;
    int tid = threadIdx.x;
    if (blk < 2048) {
        if (tid < 8) minb[blk * 8 + tid] = 0xFFFFFFFFu;
        if (blk == 0 && tid == 8) *cnt2 = 0u;
        __shared__ float t[64][65];
        __shared__ float ls[4];
        int b  = blk >> 7;
        int dt = (blk >> 4) & 7;
        int nt = blk & 15;
        int d0 = dt * 64, n0 = nt * 64;
        const float* zp = z + ((size_t)b * D + d0) * HW + n0;
        float s = 0.f;                      // z^2 partial, computed inline on load
#pragma unroll
        for (int i = 0; i < 4; ++i) {
            int e = tid + 256 * i;          // r(64 ch) x c4(16)
            int r = e >> 4, c4 = e & 15;
            float4 v = *(const float4*)(zp + (size_t)r * HW + c4 * 4);
            s += v.x * v.x + v.y * v.y + v.z * v.z + v.w * v.w;
            t[r][c4 * 4 + 0] = v.x; t[r][c4 * 4 + 1] = v.y;
            t[r][c4 * 4 + 2] = v.z; t[r][c4 * 4 + 3] = v.w;
        }
#pragma unroll
        for (int o = 32; o; o >>= 1) s += __shfl_down(s, o);
        if ((tid & 63) == 0) ls[tid >> 6] = s;
        __syncthreads();
        if (tid == 0) pz[blk] = ls[0] + ls[1] + ls[2] + ls[3];   // plain store, no atomic
        // transposed store: R7-proven ushort4 pattern (4 scalar LDS reads per 8 B store)
        __hip_bfloat16* op = zb + ((size_t)(b * HW + n0)) * D + d0;
#pragma unroll
        for (int i = 0; i < 4; ++i) {
            int e = tid + 256 * i;          // rn(64 tok) x cd4(16)
            int rn = e >> 4, cd4 = e & 15;
            __hip_bfloat16 q0 = __float2bfloat16(t[cd4 * 4 + 0][rn]);
            __hip_bfloat16 q1 = __float2bfloat16(t[cd4 * 4 + 1][rn]);
            __hip_bfloat16 q2 = __float2bfloat16(t[cd4 * 4 + 2][rn]);
            __hip_bfloat16 q3 = __float2bfloat16(t[cd4 * 4 + 3][rn]);
            ushort4 u;
            u.x = *(unsigned short*)&q0; u.y = *(unsigned short*)&q1;
            u.z = *(unsigned short*)&q2; u.w = *(unsigned short*)&q3;
            *(ushort4*)(op + (size_t)rn * D + cd4 * 4) = u;
        }
    } else {
        int k = blk - 2048;
        const float* ep = emb + (size_t)k * D;
        float s = 0.f;
        for (int d = tid; d < D; d += 256) {
            float v = ep[d];
            s += v * v;
            eb[(size_t)k * D + d] = __float2bfloat16(v);
        }
#pragma unroll
        for (int o = 32; o; o >>= 1) s += __shfl_down(s, o);
        __shared__ float ls[4];
        if ((tid & 63) == 0) ls[tid >> 6] = s;
        __syncthreads();
        if (tid == 0) esq[k] = ls[0] + ls[1] + ls[2] + ls[3];
    }
}

// ---------------- Kernel G: bf16 MFMA GEMM + fused argmin (proven, ~63.5 us — FROZEN) ----------------
// grid 2048 blocks = 128 mtiles x 16 ktiles (16 consecutive blocks share the A strip,
// dispatched simultaneously across XCDs). LDS XOR col swizzle -> 0 bank conflicts.
__global__ __launch_bounds__(256) void kg(const __hip_bfloat16* __restrict__ zb,
                                          const __hip_bfloat16* __restrict__ eb,
                                          const float* __restrict__ esq,
                                          unsigned int* __restrict__ minb) {
    __shared__ __hip_bfloat16 As[128 * 64];   // flat, unpadded (global_load_lds dest)
    __shared__ __hip_bfloat16 Bs[128 * 64];

    int mtile = blockIdx.x >> 4;
    int ktile = blockIdx.x & 15;

    int tid  = threadIdx.x;
    int wv   = tid >> 6;
    int lane = tid & 63;
    int wm = wv >> 1, wn = wv & 1;   // 2x2 wave grid, each wave 64x64
    int lrow  = lane & 15;
    int lquad = lane >> 4;
    int rl = lane >> 3, c8 = lane & 7;      // staging: 8 rows x 8 uint4 per wave-call
    int csw = c8 ^ rl;                      // swizzled global col for this lane's slot
    int swz = lrow & 7;                     // read-side row swizzle

    floatx4 acc[4][4];
#pragma unroll
    for (int i = 0; i < 4; ++i)
#pragma unroll
        for (int j = 0; j < 4; ++j) acc[i][j] = (floatx4){0.f, 0.f, 0.f, 0.f};

    const uint4* Ag = (const uint4*)(zb + (size_t)mtile * 128 * D);  // [128][64] uint4
    const uint4* Bg = (const uint4*)(eb + (size_t)ktile * 128 * D);

    for (int d0 = 0; d0 < D; d0 += 64) {
        int c0 = d0 >> 3;   // uint4 col offset
#pragma unroll
        for (int ch = 0; ch < 4; ++ch) {
            int rbase = wv * 32 + ch * 8;    // wave-uniform
            GLD_LDS16(Ag + (size_t)(rbase + rl) * 64 + c0 + csw, &As[rbase * 64]);
            GLD_LDS16(Bg + (size_t)(rbase + rl) * 64 + c0 + csw, &Bs[rbase * 64]);
        }
        __syncthreads();
#pragma unroll
        for (int ks = 0; ks < 2; ++ks) {
            short8 af[4], bfr[4];
#pragma unroll
            for (int i = 0; i < 4; ++i) {
                int cL = (ks * 4 + lquad) ^ swz;          // swizzled uint4 col
                af[i]  = *(const short8*)&As[(wm * 64 + i * 16 + lrow) * 64 + (cL << 3)];
                bfr[i] = *(const short8*)&Bs[(wn * 64 + i * 16 + lrow) * 64 + (cL << 3)];
            }
#pragma unroll
            for (int i = 0; i < 4; ++i)
#pragma unroll
                for (int j = 0; j < 4; ++j)
                    acc[i][j] = __builtin_amdgcn_mfma_f32_16x16x32_bf16(af[i], bfr[j], acc[i][j], 0, 0, 0);
        }
        __syncthreads();
    }

    // epilogue: dist = esq[k] - 2*dot; argmin via u32 key = trunc-fkey | idx
    float es[4];
#pragma unroll
    for (int j = 0; j < 4; ++j) es[j] = esq[ktile * 128 + wn * 64 + j * 16 + lrow];

#pragma unroll
    for (int i = 0; i < 4; ++i) {
#pragma unroll
        for (int r = 0; r < 4; ++r) {
            int m_g = mtile * 128 + wm * 64 + i * 16 + lquad * 4 + r;  // C/D: row=quad*4+reg
            unsigned int best = 0xFFFFFFFFu;
#pragma unroll
            for (int j = 0; j < 4; ++j) {
                float dist = es[j] - 2.0f * acc[i][j][r];
                unsigned int kidx = (unsigned int)(ktile * 128 + wn * 64 + j * 16 + lrow);
                unsigned int p = (fkey(dist) & 0xFFFFF800u) | kidx;
                best = p < best ? p : best;
            }
#pragma unroll
            for (int o = 1; o < 16; o <<= 1) {
                unsigned int other = __shfl_xor(best, o);
                best = other < best ? other : best;
            }
            if (lrow == 0) atomicMin(&minb[m_g], best);
        }
    }
}

// ---------------- Kernel O3: gather + NCHW write + loss, double-buffered (R7-proven) ----------------
// 512 blocks x 256 thr: block = 64-token strip x 256-channel half, processed as
// 4 subtiles of 64 channels with double-buffered qt (ONE barrier per subtile).
__global__ __launch_bounds__(256) void ko3(const float* __restrict__ emb,
                                           const unsigned int* __restrict__ minb,
                                           const float* __restrict__ pz,
                                           float* __restrict__ out,
                                           float* __restrict__ parts,
                                           unsigned int* __restrict__ cnt2) {
    __shared__ int idx[64];
    __shared__ float qt[2][64][65];   // 33.3 KB, 65-stride: conflict-free both phases
    __shared__ float red[4];
    __shared__ int finflag;
    int blk = blockIdx.x;
    int strip = blk >> 1;             // 0..255 : token strip (b, hw0..hw0+63)
    int chalf = blk & 1;              // channel half
    int b = strip >> 4, hw0 = (strip & 15) * 64;
    int tid = threadIdx.x;
    unsigned int mykey = 0;
    if (tid < 64) {
        mykey = minb[strip * 64 + tid];
        idx[tid] = (int)(mykey & 0x7FFu);
    }
    if (tid == 0) finflag = 0;
    __syncthreads();

    // ---- loss partial (chalf==0 blocks cover each token once) ----
    if (chalf == 0 && tid < 64) {
        float v = unfkey(mykey & 0xFFFFF800u);   // min(esq - 2 dot) for this token
#pragma unroll
        for (int o = 32; o; o >>= 1) v += __shfl_down(v, o);
        if (tid == 0) {
            parts[strip] = v;
            __threadfence();
            finflag = (atomicAdd(cnt2, 1u) == 255u);
        }
    }

    // ---- 4 subtiles, double-buffered ----
#pragma unroll
    for (int s = 0; s < 4; ++s) {
        int c0 = chalf * 256 + s * 64;
        int p = s & 1;
        // gather subtile s into buf p (overlaps writes of subtile s-1 from buf p^1)
#pragma unroll
        for (int i = 0; i < 4; ++i) {
            int e = tid + 256 * i;           // tr(64) x c4(16): 256 B coalesced rows
            int tr = e >> 4, c4 = e & 15;
            float4 v = *(const float4*)(emb + (size_t)idx[tr] * D + c0 + c4 * 4);
            qt[p][tr][c4 * 4 + 0] = v.x; qt[p][tr][c4 * 4 + 1] = v.y;
            qt[p][tr][c4 * 4 + 2] = v.z; qt[p][tr][c4 * 4 + 3] = v.w;
        }
        __syncthreads();                     // buf p stores visible; prev-iter reads done
        float* op = out + ((size_t)b * D + c0) * HW + hw0;
#pragma unroll
        for (int i = 0; i < 4; ++i) {
            int e = tid + 256 * i;           // r(64 ch) x h4(16), float4 along hw
            int r = e >> 4, h4 = e & 15;
            float4 q;
            q.x = qt[p][h4 * 4 + 0][r]; q.y = qt[p][h4 * 4 + 1][r];
            q.z = qt[p][h4 * 4 + 2][r]; q.w = qt[p][h4 * 4 + 3][r];
            *(float4*)(op + (size_t)r * HW + h4 * 4) = q;
        }
    }

    // ---- final loss reduce by the last-finishing chalf==0 block ----
    __syncthreads();
    if (finflag) {
        float sv = atomicAdd(&parts[tid], 0.0f);    // coherent read of 256 strip partials
#pragma unroll
        for (int k8 = 0; k8 < 8; ++k8) sv += pz[tid * 8 + k8];   // fold 2048 z^2 partials
#pragma unroll
        for (int o = 32; o; o >>= 1) sv += __shfl_down(sv, o);
        if ((tid & 63) == 0) red[tid >> 6] = sv;
        __syncthreads();
        if (tid == 0)
            out[NUMEL] = 1.25f * (red[0] + red[1] + red[2] + red[3]) / 8388608.0f;
    }
}

extern "C" void kernel_launch(void* const* d_in, const int* in_sizes, int n_in,
                              void* d_out, int out_size, void* d_ws, size_t ws_size,
                              hipStream_t stream) {
    const float* z   = (const float*)d_in[0];   // [16,512,32,32]
    const float* emb = (const float*)d_in[1];   // [2048,512]
    char* ws = (char*)d_ws;
    __hip_bfloat16* zb   = (__hip_bfloat16*)(ws + WS_ZB);
    __hip_bfloat16* eb   = (__hip_bfloat16*)(ws + WS_EB);
    float*          esq  = (float*)(ws + WS_ESQ);
    unsigned int*   minb = (unsigned int*)(ws + WS_MINB);
    float*          pz   = (float*)(ws + WS_PZ);
    float*          parts= (float*)(ws + WS_PARTS);
    unsigned int*   cnt2 = (unsigned int*)(ws + WS_CNT2);
    float* out = (float*)d_out;

    kp <<<4096, 256, 0, stream>>>(z, emb, zb, eb, esq, pz, minb, cnt2);
    kg <<<2048, 256, 0, stream>>>(zb, eb, esq, minb);
    ko3<<< 512, 256, 0, stream>>>(emb, minb, pz, out, parts, cnt2);
}